// Round 8
// baseline (80.699 us; speedup 1.0000x reference)
//
#include <hip/hip_runtime.h>

typedef _Float16 f16;
typedef _Float16 f16x8 __attribute__((ext_vector_type(8)));
typedef float f32x4 __attribute__((ext_vector_type(4)));

typedef __attribute__((address_space(1))) void gvoid;
typedef __attribute__((address_space(3))) void lvoid;
#define GLD16(gp, lp) __builtin_amdgcn_global_load_lds((gvoid*)(gp), (lvoid*)(lp), 16, 0, 0)

__device__ __forceinline__ f32x4 mfma16(f16x8 a, f16x8 b, f32x4 c) {
    return __builtin_amdgcn_mfma_f32_16x16x32_f16(a, b, c, 0, 0, 0);
}

// ---- prep: LN (blocks 0..2047) + wqkv transpose (2048..2239) + wout transpose (2240..2303)
__global__ __launch_bounds__(256) void k_prep(
    const float* __restrict__ x, const float* __restrict__ gamma,
    const float* __restrict__ beta, const int* __restrict__ mlab,
    const float* __restrict__ wqkv, const float* __restrict__ wout,
    f16* __restrict__ h, f16* __restrict__ wqkvT, f16* __restrict__ woutT)
{
    __shared__ float t[64][65];
    int bid = blockIdx.x, tid = threadIdx.x;
    if (bid < 2048) {                       // ---- LayerNorm, 1 wave/row ----
        int row = bid * 4 + (tid >> 6);
        int b = row >> 10, seg = (row >> 8) & 3;
        if (mlab[b * 4 + seg] == 0) return; // h rows of missing segs never read
        int lane = tid & 63;
        const float* xr = x + (size_t)row * 512;
        float4 a = ((const float4*)xr)[lane * 2];
        float4 bv = ((const float4*)xr)[lane * 2 + 1];
        float v[8] = {a.x, a.y, a.z, a.w, bv.x, bv.y, bv.z, bv.w};
        float s = 0.f, s2 = 0.f;
#pragma unroll
        for (int j = 0; j < 8; ++j) { s += v[j]; s2 += v[j] * v[j]; }
#pragma unroll
        for (int off = 1; off < 64; off <<= 1) {
            s  += __shfl_xor(s, off);
            s2 += __shfl_xor(s2, off);
        }
        float mu  = s * (1.f / 512.f);
        float var = s2 * (1.f / 512.f) - mu * mu;
        float rstd = rsqrtf(var + 1e-5f);
        float4 g0 = ((const float4*)gamma)[lane * 2];
        float4 g1 = ((const float4*)gamma)[lane * 2 + 1];
        float4 b0 = ((const float4*)beta)[lane * 2];
        float4 b1 = ((const float4*)beta)[lane * 2 + 1];
        float g[8]  = {g0.x, g0.y, g0.z, g0.w, g1.x, g1.y, g1.z, g1.w};
        float bb[8] = {b0.x, b0.y, b0.z, b0.w, b1.x, b1.y, b1.z, b1.w};
        f16x8 o;
#pragma unroll
        for (int j = 0; j < 8; ++j) o[j] = (f16)((v[j] - mu) * rstd * g[j] + bb[j]);
        *(f16x8*)&h[(size_t)row * 512 + lane * 8] = o;
        return;
    }
    // ---- weight transpose + f16 cast via LDS tile ----
    const float* in; f16* out; int C, c0, r0;
    if (bid < 2240) { int idx = bid - 2048; in = wqkv; out = wqkvT; C = 1536; c0 = (idx % 24) * 64; r0 = (idx / 24) * 64; }
    else            { int idx = bid - 2240; in = wout; out = woutT; C = 512;  c0 = (idx % 8)  * 64; r0 = (idx / 8)  * 64; }
#pragma unroll
    for (int i = 0; i < 16; ++i) {
        int r = i * 4 + (tid >> 6), c = tid & 63;
        t[r][c] = in[(size_t)(r0 + r) * C + c0 + c];
    }
    __syncthreads();
#pragma unroll
    for (int i = 0; i < 16; ++i) {
        int cr = i * 4 + (tid >> 6), cc = tid & 63;
        out[(size_t)(c0 + cr) * 512 + r0 + cc] = (f16)t[cc][cr];
    }
}

// ---- QKV GEMM: 64x128 tile, BK=64, LDS dbuf, single barrier/K-step, swizzled ----
__global__ __launch_bounds__(256, 3) void k_gemm_qkv(
    const f16* __restrict__ A, const f16* __restrict__ Bt, const int* __restrict__ mlab,
    f16* __restrict__ q, f16* __restrict__ kmat, f16* __restrict__ vt)
{
    __shared__ f16 As[2][64 * 64];
    __shared__ f16 Bs[2][128 * 64];
    int tid = threadIdx.x, wid = tid >> 6, lane = tid & 63;
    int wm = wid >> 1, wn = wid & 1;
    int l15 = lane & 15, l4 = lane >> 4;
    int rowBase = blockIdx.y * 64;
    int colBase = blockIdx.x * 128;
    if (mlab[(rowBase >> 10) * 4 + ((rowBase & 1023) >> 8)] == 0) return;

    int srow = lane >> 3;
    int scolz = ((lane & 7) ^ srow) << 3;    // inverse-swizzled source col (rule #21)
    int kxor = (l15 & 7) << 3;

#define STG(bi, kt)                                                                         \
    do {                                                                                    \
        _Pragma("unroll") for (int i_ = 0; i_ < 2; ++i_) {                                  \
            int rg = (wid * 2 + i_) * 8;                                                    \
            GLD16(&A[(size_t)(rowBase + rg + srow) * 512 + (kt) + scolz], &As[bi][rg * 64]);\
        }                                                                                   \
        _Pragma("unroll") for (int i_ = 0; i_ < 4; ++i_) {                                  \
            int rg = (wid * 4 + i_) * 8;                                                    \
            GLD16(&Bt[(size_t)(colBase + rg + srow) * 512 + (kt) + scolz], &Bs[bi][rg * 64]);\
        }                                                                                   \
    } while (0)

    f32x4 acc[2][4] = {};
    STG(0, 0);
    for (int ki = 0; ki < 8; ++ki) {
        int bi = ki & 1;
        __syncthreads();                    // buf bi staged; all waves done with bi^1
        if (ki < 7) STG(bi ^ 1, (ki + 1) * 64);
#pragma unroll
        for (int kk = 0; kk < 2; ++kk) {
            f16x8 af[2], bf[4];
#pragma unroll
            for (int m = 0; m < 2; ++m)
                af[m] = *(const f16x8*)&As[bi][(wm * 32 + m * 16 + l15) * 64 + ((kk * 32 + l4 * 8) ^ kxor)];
#pragma unroll
            for (int n = 0; n < 4; ++n)
                bf[n] = *(const f16x8*)&Bs[bi][(wn * 64 + n * 16 + l15) * 64 + ((kk * 32 + l4 * 8) ^ kxor)];
#pragma unroll
            for (int m = 0; m < 2; ++m)
#pragma unroll
                for (int n = 0; n < 4; ++n)
                    acc[m][n] = mfma16(af[m], bf[n], acc[m][n]);
        }
    }
#undef STG
#pragma unroll
    for (int m = 0; m < 2; ++m)
#pragma unroll
        for (int n = 0; n < 4; ++n)
#pragma unroll
            for (int r = 0; r < 4; ++r) {
                int row = rowBase + wm * 32 + m * 16 + l4 * 4 + r;
                int col = colBase + wn * 64 + n * 16 + l15;
                f16 hv = (f16)acc[m][n][r];
                int b = row >> 10, nt = row & 1023;
                int which = col >> 9, hh = (col >> 6) & 7, d = col & 63;
                size_t hidx = ((size_t)(b * 8 + hh) * 1024 + nt) * 64 + d;
                if (which == 0)      q[hidx] = hv;
                else if (which == 1) kmat[hidx] = hv;
                else                 vt[((size_t)(b * 8 + hh) * 64 + d) * 1024 + nt] = hv;
            }
}

// ---- masked flash attention v8: split-K groups, single-buf LDS + T14 reg-staging ----
// 1024 blocks x 512 threads. wid = qs(0..3) | g<<2. Group g handles chunks 2i+g.
// 32KB LDS -> 3 blocks/CU; prefetch via regs so barriers don't expose HBM latency.
__global__ __launch_bounds__(512, 6) void k_attn(
    const f16* __restrict__ q, const f16* __restrict__ kmat,
    const f16* __restrict__ vt, const int* __restrict__ mlab,
    f16* __restrict__ ao)
{
    __shared__ f16 Ks[2][64 * 64];          // [group], single-buffered (8KB each)
    __shared__ f16 Vs[2][64 * 64];

    int bid = blockIdx.x;
    int bh = (bid & 7) + 8 * (bid >> 7);    // all 16 q-blocks of a bh on one XCD
    int qb = (bid >> 3) & 15;
    int b = bh >> 3, hh = bh & 7;
    int tid = threadIdx.x, wid = tid >> 6, lane = tid & 63;
    int qs = wid & 3, g = wid >> 2;
    int l15 = lane & 15, l4 = lane >> 4;
    int qbase = qb * 64;
    size_t bhs = (size_t)bh;

    if (mlab[b * 4 + (qb >> 2)] == 0) return;   // rows filled by k_gemm_out bias path

    unsigned long long chpack = 0; int nch = 0; // nch is a multiple of 4
#pragma unroll
    for (int s = 0; s < 4; ++s)
        if (mlab[b * 4 + s] != 0) {
#pragma unroll
            for (int j = 0; j < 4; ++j) {
                chpack |= (unsigned long long)(4 * s + j) << (4 * nch);
                ++nch;
            }
        }
    int niter = nch >> 1;                   // chunks per group (>=2, even)

    f16x8 qf[2];
#pragma unroll
    for (int kk = 0; kk < 2; ++kk) {
        qf[kk] = *(const f16x8*)&q[(bhs * 1024 + qbase + qs * 16 + l15) * 64 + kk * 32 + l4 * 8];
#pragma unroll
        for (int j = 0; j < 8; ++j) qf[kk][j] = qf[kk][j] * (f16)0.125;
    }

    // group-local staging: 256 threads (gtid) cover 512 16B slots (2 each),
    // inverse-swizzled global source column (rule #21)
    int gtid = tid & 255;
    int srow0 = gtid >> 3;
    int sc0 = ((gtid & 7) ^ (srow0 & 7)) << 3;
    int srow1 = (gtid + 256) >> 3;
    int sc1 = (((gtid + 256) & 7) ^ (srow1 & 7)) << 3;

    int4 krA, krB, vrA, vrB;
#define LOADREG(t0)                                                                     \
    do {                                                                                \
        krA = *(const int4*)&kmat[(bhs * 1024 + (t0) + srow0) * 64 + sc0];              \
        krB = *(const int4*)&kmat[(bhs * 1024 + (t0) + srow1) * 64 + sc1];              \
        vrA = *(const int4*)&vt[(bhs * 64 + srow0) * 1024 + (t0) + sc0];                \
        vrB = *(const int4*)&vt[(bhs * 64 + srow1) * 1024 + (t0) + sc1];                \
    } while (0)

    float mrun = -1e30f, lrun = 0.f;
    f32x4 o[4] = {};
    int kxor = (l15 & 7) << 3;
    int srcA = l15 + ((l4 & 1) * 2) * 16;
    int srcB = srcA + 16;
    int sel = l4 >> 1;

    LOADREG((int)((chpack >> (4 * g)) & 15) << 6);   // group g's first chunk

    for (int i = 0; i < niter; ++i) {
        // write staged regs to LDS (implicit vmcnt wait was covered by prev compute)
        *(int4*)&Ks[g][gtid * 8] = krA;
        *(int4*)&Ks[g][(gtid + 256) * 8] = krB;
        *(int4*)&Vs[g][gtid * 8] = vrA;
        *(int4*)&Vs[g][(gtid + 256) * 8] = vrB;
        __syncthreads();                    // tiles ready (only LDS writes to drain)
        if (i + 1 < niter) {                // T14: issue next chunk's loads early
            int cn = 2 * (i + 1) + g;
            LOADREG((int)((chpack >> (4 * cn)) & 15) << 6);
        }

        // QK^T swapped: st[n] = S^T, k = n*16 + l4*4 + r, q-col = l15
        f32x4 st[4] = {};
        __builtin_amdgcn_s_setprio(1);
#pragma unroll
        for (int kk = 0; kk < 2; ++kk)
#pragma unroll
            for (int n = 0; n < 4; ++n) {
                f16x8 ka = *(const f16x8*)&Ks[g][(n * 16 + l15) * 64 + ((kk * 32 + l4 * 8) ^ kxor)];
                st[n] = mfma16(ka, qf[kk], st[n]);
            }
        __builtin_amdgcn_s_setprio(0);

        // lane-local online softmax over this lane's 16 k-values
        f32x4 m4 = st[0];
#pragma unroll
        for (int n = 1; n < 4; ++n)
#pragma unroll
            for (int r = 0; r < 4; ++r) m4[r] = fmaxf(m4[r], st[n][r]);
        float mx = fmaxf(fmaxf(m4[0], m4[1]), fmaxf(m4[2], m4[3]));
        mx = fmaxf(mx, __shfl_xor(mx, 16));
        mx = fmaxf(mx, __shfl_xor(mx, 32));
        float mnew = fmaxf(mrun, mx);
        float alpha = __expf(mrun - mnew);
        mrun = mnew;
        float rs = 0.f;
        union PK { f16 h[4]; long long ll; } pk[4];
#pragma unroll
        for (int n = 0; n < 4; ++n)
#pragma unroll
            for (int r = 0; r < 4; ++r) {
                float p = __expf(st[n][r] - mnew);
                rs += p;
                pk[n].h[r] = (f16)p;
            }
        rs += __shfl_xor(rs, 16);
        rs += __shfl_xor(rs, 32);
        lrun = lrun * alpha + rs;
#pragma unroll
        for (int nd = 0; nd < 4; ++nd) o[nd] *= alpha;

        // P redistribution within 4-lane groups + PV
#pragma unroll
        for (int ks = 0; ks < 2; ++ks) {
            long long A0 = __shfl(pk[ks * 2].ll,     srcA);
            long long A1 = __shfl(pk[ks * 2 + 1].ll, srcA);
            long long B0 = __shfl(pk[ks * 2].ll,     srcB);
            long long B1 = __shfl(pk[ks * 2 + 1].ll, srcB);
            union PB { long long ll[2]; f16x8 v; } pb;
            pb.ll[0] = sel ? A1 : A0;
            pb.ll[1] = sel ? B1 : B0;
            __builtin_amdgcn_s_setprio(1);
#pragma unroll
            for (int nd = 0; nd < 4; ++nd) {
                f16x8 va = *(const f16x8*)&Vs[g][(nd * 16 + l15) * 64 + ((ks * 32 + l4 * 8) ^ kxor)];
                o[nd] = mfma16(va, pb.v, o[nd]);
            }
            __builtin_amdgcn_s_setprio(0);
        }
        __syncthreads();                    // group done reading before next overwrite
    }
#undef LOADREG

    // ---- 2-way split-K merge (aliases LDS, all compute done) ----
    float* mg  = (float*)&Ks[0][0];         // 4*64*16 f32 = 16KB (o partials, group 1)
    float* mml = (float*)&Vs[0][0];         // 128 f32 (m, l of group 1)
    if (g == 1) {
        if (l4 == 0) { mml[qs * 16 + l15] = mrun; mml[64 + qs * 16 + l15] = lrun; }
#pragma unroll
        for (int nd = 0; nd < 4; ++nd)
#pragma unroll
            for (int r = 0; r < 4; ++r)
                mg[(qs * 64 + nd * 16 + l4 * 4 + r) * 16 + l15] = o[nd][r];
    }
    __syncthreads();
    if (g == 0) {
        float m1 = mml[qs * 16 + l15], l1 = mml[64 + qs * 16 + l15];
        float mst = fmaxf(mrun, m1);
        float e0 = __expf(mrun - mst), e1 = __expf(m1 - mst);
        float inv = 1.f / (lrun * e0 + l1 * e1);
        int qrow = qbase + qs * 16 + l15;
#pragma unroll
        for (int nd = 0; nd < 4; ++nd) {
            union { f16 h[4]; long long ll; } w;
#pragma unroll
            for (int r = 0; r < 4; ++r)
                w.h[r] = (f16)((o[nd][r] * e0 + mg[(qs * 64 + nd * 16 + l4 * 4 + r) * 16 + l15] * e1) * inv);
            *(long long*)&ao[(size_t)(b * 1024 + qrow) * 512 + hh * 64 + nd * 16 + l4 * 4] = w.ll;
        }
    }
}

// ---- out GEMM: 64x128 tile, LDS dbuf, single barrier/K-step, swizzled ----
__global__ __launch_bounds__(256, 3) void k_gemm_out(
    const f16* __restrict__ A, const f16* __restrict__ Bt, const int* __restrict__ mlab,
    const float* __restrict__ bias, float* __restrict__ out)
{
    __shared__ f16 As[2][64 * 64];
    __shared__ f16 Bs[2][128 * 64];
    int tid = threadIdx.x, wid = tid >> 6, lane = tid & 63;
    int wm = wid >> 1, wn = wid & 1;
    int l15 = lane & 15, l4 = lane >> 4;
    int rowBase = blockIdx.y * 64;
    int colBase = blockIdx.x * 128;
    if (mlab[(rowBase >> 10) * 4 + ((rowBase & 1023) >> 8)] == 0) {
        for (int i = tid; i < 64 * 128; i += 256)
            out[(size_t)(rowBase + (i >> 7)) * 512 + colBase + (i & 127)] = bias[colBase + (i & 127)];
        return;
    }

    int srow = lane >> 3;
    int scolz = ((lane & 7) ^ srow) << 3;
    int kxor = (l15 & 7) << 3;

#define STG(bi, kt)                                                                         \
    do {                                                                                    \
        _Pragma("unroll") for (int i_ = 0; i_ < 2; ++i_) {                                  \
            int rg = (wid * 2 + i_) * 8;                                                    \
            GLD16(&A[(size_t)(rowBase + rg + srow) * 512 + (kt) + scolz], &As[bi][rg * 64]);\
        }                                                                                   \
        _Pragma("unroll") for (int i_ = 0; i_ < 4; ++i_) {                                  \
            int rg = (wid * 4 + i_) * 8;                                                    \
            GLD16(&Bt[(size_t)(colBase + rg + srow) * 512 + (kt) + scolz], &Bs[bi][rg * 64]);\
        }                                                                                   \
    } while (0)

    f32x4 acc[2][4] = {};
    STG(0, 0);
    for (int ki = 0; ki < 8; ++ki) {
        int bi = ki & 1;
        __syncthreads();
        if (ki < 7) STG(bi ^ 1, (ki + 1) * 64);
#pragma unroll
        for (int kk = 0; kk < 2; ++kk) {
            f16x8 af[2], bf[4];
#pragma unroll
            for (int m = 0; m < 2; ++m)
                af[m] = *(const f16x8*)&As[bi][(wm * 32 + m * 16 + l15) * 64 + ((kk * 32 + l4 * 8) ^ kxor)];
#pragma unroll
            for (int n = 0; n < 4; ++n)
                bf[n] = *(const f16x8*)&Bs[bi][(wn * 64 + n * 16 + l15) * 64 + ((kk * 32 + l4 * 8) ^ kxor)];
#pragma unroll
            for (int m = 0; m < 2; ++m)
#pragma unroll
                for (int n = 0; n < 4; ++n)
                    acc[m][n] = mfma16(af[m], bf[n], acc[m][n]);
        }
    }
#undef STG
#pragma unroll
    for (int m = 0; m < 2; ++m)
#pragma unroll
        for (int n = 0; n < 4; ++n)
#pragma unroll
            for (int r = 0; r < 4; ++r) {
                int row = rowBase + wm * 32 + m * 16 + l4 * 4 + r;
                int col = colBase + wn * 64 + n * 16 + l15;
                out[(size_t)row * 512 + col] = acc[m][n][r] + bias[col];
            }
}

extern "C" void kernel_launch(void* const* d_in, const int* in_sizes, int n_in,
                              void* d_out, int out_size, void* d_ws, size_t ws_size,
                              hipStream_t stream) {
    const float* x     = (const float*)d_in[0];
    const int*   mlab  = (const int*)d_in[1];
    const float* gamma = (const float*)d_in[2];
    const float* beta  = (const float*)d_in[3];
    const float* wqkv  = (const float*)d_in[4];
    const float* wout  = (const float*)d_in[5];
    const float* bout  = (const float*)d_in[6];
    float* out = (float*)d_out;

    f16* h     = (f16*)d_ws;                 // 8192*512
    f16* wqkvT = h + 8192 * 512;             // 1536*512
    f16* woutT = wqkvT + 1536 * 512;         // 512*512
    f16* q     = woutT + 512 * 512;          // [B*H][1024][64]
    f16* kmat  = q + 4 * 1024 * 1024;
    f16* vt    = kmat + 4 * 1024 * 1024;     // [B*H][64][1024]
    f16* ao    = h;                          // h dead after QKV GEMM -> reuse

    k_prep<<<2304, 256, 0, stream>>>(x, gamma, beta, mlab, wqkv, wout, h, wqkvT, woutT);
    k_gemm_qkv<<<dim3(12, 128), 256, 0, stream>>>(h, wqkvT, mlab, q, kmat, vt);
    k_attn<<<1024, 512, 0, stream>>>(q, kmat, vt, mlab, ao);
    k_gemm_out<<<dim3(4, 128), 256, 0, stream>>>(ao, woutT, mlab, bout, out);
}

// Round 9
// 62.155 us; speedup vs baseline: 1.2984x; 1.2984x over previous
//
#include <hip/hip_runtime.h>

typedef _Float16 f16;
typedef _Float16 f16x8 __attribute__((ext_vector_type(8)));
typedef float f32x4 __attribute__((ext_vector_type(4)));

typedef __attribute__((address_space(1))) void gvoid;
typedef __attribute__((address_space(3))) void lvoid;
#define GLD16(gp, lp) __builtin_amdgcn_global_load_lds((gvoid*)(gp), (lvoid*)(lp), 16, 0, 0)

__device__ __forceinline__ f32x4 mfma16(f16x8 a, f16x8 b, f32x4 c) {
    return __builtin_amdgcn_mfma_f32_16x16x32_f16(a, b, c, 0, 0, 0);
}

// ---- prep: LN (blocks 0..2047) + wqkv transpose (2048..2239) + wout transpose (2240..2303)
__global__ __launch_bounds__(256) void k_prep(
    const float* __restrict__ x, const float* __restrict__ gamma,
    const float* __restrict__ beta, const int* __restrict__ mlab,
    const float* __restrict__ wqkv, const float* __restrict__ wout,
    f16* __restrict__ h, f16* __restrict__ wqkvT, f16* __restrict__ woutT)
{
    __shared__ float t[64][65];
    int bid = blockIdx.x, tid = threadIdx.x;
    if (bid < 2048) {                       // ---- LayerNorm, 1 wave/row ----
        int row = bid * 4 + (tid >> 6);
        int b = row >> 10, seg = (row >> 8) & 3;
        if (mlab[b * 4 + seg] == 0) return;
        int lane = tid & 63;
        const float* xr = x + (size_t)row * 512;
        float4 a = ((const float4*)xr)[lane * 2];
        float4 bv = ((const float4*)xr)[lane * 2 + 1];
        float v[8] = {a.x, a.y, a.z, a.w, bv.x, bv.y, bv.z, bv.w};
        float s = 0.f, s2 = 0.f;
#pragma unroll
        for (int j = 0; j < 8; ++j) { s += v[j]; s2 += v[j] * v[j]; }
#pragma unroll
        for (int off = 1; off < 64; off <<= 1) {
            s  += __shfl_xor(s, off);
            s2 += __shfl_xor(s2, off);
        }
        float mu  = s * (1.f / 512.f);
        float var = s2 * (1.f / 512.f) - mu * mu;
        float rstd = rsqrtf(var + 1e-5f);
        float4 g0 = ((const float4*)gamma)[lane * 2];
        float4 g1 = ((const float4*)gamma)[lane * 2 + 1];
        float4 b0 = ((const float4*)beta)[lane * 2];
        float4 b1 = ((const float4*)beta)[lane * 2 + 1];
        float g[8]  = {g0.x, g0.y, g0.z, g0.w, g1.x, g1.y, g1.z, g1.w};
        float bb[8] = {b0.x, b0.y, b0.z, b0.w, b1.x, b1.y, b1.z, b1.w};
        f16x8 o;
#pragma unroll
        for (int j = 0; j < 8; ++j) o[j] = (f16)((v[j] - mu) * rstd * g[j] + bb[j]);
        *(f16x8*)&h[(size_t)row * 512 + lane * 8] = o;
        return;
    }
    const float* in; f16* out; int C, c0, r0;
    if (bid < 2240) { int idx = bid - 2048; in = wqkv; out = wqkvT; C = 1536; c0 = (idx % 24) * 64; r0 = (idx / 24) * 64; }
    else            { int idx = bid - 2240; in = wout; out = woutT; C = 512;  c0 = (idx % 8)  * 64; r0 = (idx / 8)  * 64; }
#pragma unroll
    for (int i = 0; i < 16; ++i) {
        int r = i * 4 + (tid >> 6), c = tid & 63;
        t[r][c] = in[(size_t)(r0 + r) * C + c0 + c];
    }
    __syncthreads();
#pragma unroll
    for (int i = 0; i < 16; ++i) {
        int cr = i * 4 + (tid >> 6), cc = tid & 63;
        out[(size_t)(c0 + cr) * 512 + r0 + cc] = (f16)t[cc][cr];
    }
}

// ---- QKV GEMM: 64x128 tile, BK=64, LDS dbuf, swizzled; LDS-repacked 16B epilogue ----
__global__ __launch_bounds__(256, 3) void k_gemm_qkv(
    const f16* __restrict__ A, const f16* __restrict__ Bt, const int* __restrict__ mlab,
    f16* __restrict__ q, f16* __restrict__ kmat, f16* __restrict__ vt)
{
    __shared__ __align__(16) f16 SM[24576];   // As: bi*4096 (64x64); Bs: 8192+bi*8192 (128x64); epilogue T aliases SM
    int tid = threadIdx.x, wid = tid >> 6, lane = tid & 63;
    int wm = wid >> 1, wn = wid & 1;
    int l15 = lane & 15, l4 = lane >> 4;
    int rowBase = blockIdx.y * 64;
    int colBase = blockIdx.x * 128;
    if (mlab[(rowBase >> 10) * 4 + ((rowBase & 1023) >> 8)] == 0) return;

    int srow = lane >> 3;
    int scolz = ((lane & 7) ^ srow) << 3;
    int kxor = (l15 & 7) << 3;

#define STG(bi, kt)                                                                              \
    do {                                                                                         \
        _Pragma("unroll") for (int i_ = 0; i_ < 2; ++i_) {                                       \
            int rg = (wid * 2 + i_) * 8;                                                         \
            GLD16(&A[(size_t)(rowBase + rg + srow) * 512 + (kt) + scolz], SM + (bi)*4096 + rg*64);\
        }                                                                                        \
        _Pragma("unroll") for (int i_ = 0; i_ < 4; ++i_) {                                       \
            int rg = (wid * 4 + i_) * 8;                                                         \
            GLD16(&Bt[(size_t)(colBase + rg + srow) * 512 + (kt) + scolz], SM + 8192 + (bi)*8192 + rg*64);\
        }                                                                                        \
    } while (0)

    f32x4 acc[2][4] = {};
    STG(0, 0);
    for (int ki = 0; ki < 8; ++ki) {
        int bi = ki & 1;
        __syncthreads();
        if (ki < 7) STG(bi ^ 1, (ki + 1) * 64);
#pragma unroll
        for (int kk = 0; kk < 2; ++kk) {
            f16x8 af[2], bf[4];
#pragma unroll
            for (int m = 0; m < 2; ++m)
                af[m] = *(const f16x8*)&SM[bi*4096 + (wm * 32 + m * 16 + l15) * 64 + ((kk * 32 + l4 * 8) ^ kxor)];
#pragma unroll
            for (int n = 0; n < 4; ++n)
                bf[n] = *(const f16x8*)&SM[8192 + bi*8192 + (wn * 64 + n * 16 + l15) * 64 + ((kk * 32 + l4 * 8) ^ kxor)];
#pragma unroll
            for (int m = 0; m < 2; ++m)
#pragma unroll
                for (int n = 0; n < 4; ++n)
                    acc[m][n] = mfma16(af[m], bf[n], acc[m][n]);
        }
    }
#undef STG

    // ---- epilogue: repack through LDS so all stores are 16B ----
    __syncthreads();                                  // staging LDS now free to alias
    bool isV = (colBase >= 1024);
    if (!isV) {                                       // q/k: T[64 nt][136 pad] (cols = 128 d)
#pragma unroll
        for (int m = 0; m < 2; ++m)
#pragma unroll
            for (int n = 0; n < 4; ++n)
#pragma unroll
                for (int r = 0; r < 4; ++r)
                    SM[(wm*32 + m*16 + l4*4 + r) * 136 + wn*64 + n*16 + l15] = (f16)acc[m][n][r];
        __syncthreads();
        int rl = tid >> 2, cl0 = (tid & 3) * 32;
        int row = rowBase + rl, bq = row >> 10, nt = row & 1023;
#pragma unroll
        for (int jj = 0; jj < 4; ++jj) {
            f16x8 v = *(const f16x8*)&SM[rl * 136 + cl0 + jj * 8];
            int col = colBase + cl0 + jj * 8;
            int which = col >> 9, hh2 = (col >> 6) & 7, d = col & 63;
            f16* dst = which ? kmat : q;
            *(f16x8*)&dst[((size_t)(bq * 8 + hh2) * 1024 + nt) * 64 + d] = v;
        }
    } else {                                          // v: T[128 d-col][72 pad] (transposed)
#pragma unroll
        for (int m = 0; m < 2; ++m)
#pragma unroll
            for (int n = 0; n < 4; ++n)
#pragma unroll
                for (int r = 0; r < 4; ++r)
                    SM[(wn*64 + n*16 + l15) * 72 + wm*32 + m*16 + l4*4 + r] = (f16)acc[m][n][r];
        __syncthreads();
        int cl = tid >> 1, rl0 = (tid & 1) * 32;
        int col = colBase + cl, hh2 = (col >> 6) & 7, d = col & 63;
        int bq = rowBase >> 10, ntb = (rowBase & 1023) + rl0;
        f16* dstrow = vt + ((size_t)(bq * 8 + hh2) * 64 + d) * 1024 + ntb;
#pragma unroll
        for (int jj = 0; jj < 4; ++jj)
            *(f16x8*)&dstrow[jj * 8] = *(const f16x8*)&SM[cl * 72 + rl0 + jj * 8];
    }
}

// ---- masked flash attention v9: 4-way split-K, 2 waves/group, 32-q-rows/wave ----
// 1024 blocks x 512 threads; 32-token chunks; dbuf GLD16; 1 barrier/iter;
// distributed 4-way merge with coalesced 16B ao stores.
__global__ __launch_bounds__(512, 4) void k_attn(
    const f16* __restrict__ q, const f16* __restrict__ kmat,
    const f16* __restrict__ vt, const int* __restrict__ mlab,
    f16* __restrict__ ao)
{
    __shared__ __align__(16) f16 KV[32768];   // K tiles: (g*2+bi)*2048; V: 16384+(g*2+bi)*2048; merge aliases as f32[4][64][64]
    __shared__ float ML[512];                 // m: [g*64+q]; l: [256+g*64+q]

    int bid = blockIdx.x;
    int bh = (bid & 7) + 8 * (bid >> 7);      // all 16 q-blocks of a bh on one XCD
    int qb = (bid >> 3) & 15;
    int b = bh >> 3, hh = bh & 7;
    int tid = threadIdx.x, wid = tid >> 6, lane = tid & 63;
    int g = wid >> 1, qs = wid & 1;
    int l15 = lane & 15, l4 = lane >> 4;
    int qbase = qb * 64;
    size_t bhs = (size_t)bh;

    if (mlab[b * 4 + (qb >> 2)] == 0) return;  // rows filled by k_gemm_out bias path

    unsigned ps = 0; int npres = 0;
#pragma unroll
    for (int s = 0; s < 4; ++s)
        if (mlab[b * 4 + s] != 0) { ps |= (unsigned)s << (4 * npres); ++npres; }
    int niter = npres * 2;                    // chunks per group (32-token chunks, /4 groups)
#define T0C(c) ((int)((ps >> (4 * ((c) >> 3))) & 15) * 256 + ((c) & 7) * 32)

    // Q fragments: rows qs*32 + m*16 + l15, pre-scaled by 1/8
    f16x8 qf0[2], qf1[2];
#pragma unroll
    for (int kk = 0; kk < 2; ++kk) {
        qf0[kk] = *(const f16x8*)&q[(bhs * 1024 + qbase + qs * 32 + l15) * 64 + kk * 32 + l4 * 8];
        qf1[kk] = *(const f16x8*)&q[(bhs * 1024 + qbase + qs * 32 + 16 + l15) * 64 + kk * 32 + l4 * 8];
#pragma unroll
        for (int j = 0; j < 8; ++j) { qf0[kk][j] = qf0[kk][j] * (f16)0.125; qf1[kk][j] = qf1[kk][j] * (f16)0.125; }
    }

    // staging geometry: group = 2 waves = 128 threads covering 256 slots (2 each)
    int sA = qs * 64 + lane, sB = sA + 128;
    int krA = sA >> 3, kcA = ((sA & 7) ^ (krA & 7)) << 3;
    int krB = sB >> 3, kcB = ((sB & 7) ^ (krB & 7)) << 3;
    int vrA = sA >> 2, vcA = ((sA & 3) ^ ((vrA >> 1) & 3)) << 3;
    int vrB = sB >> 2, vcB = ((sB & 3) ^ ((vrB >> 1) & 3)) << 3;
    const f16* kgA = kmat + (bhs * 1024 + krA) * 64 + kcA;   // + t0*64
    const f16* kgB = kmat + (bhs * 1024 + krB) * 64 + kcB;
    const f16* vgA = vt + (bhs * 64 + vrA) * 1024 + vcA;     // + t0
    const f16* vgB = vt + (bhs * 64 + vrB) * 1024 + vcB;

#define STAGE(bi, t0)                                                \
    do {                                                             \
        f16* kd = KV + (g * 2 + (bi)) * 2048 + qs * 512;             \
        f16* vd = KV + 16384 + (g * 2 + (bi)) * 2048 + qs * 512;     \
        GLD16(kgA + (size_t)(t0) * 64, kd);                          \
        GLD16(kgB + (size_t)(t0) * 64, kd + 1024);                   \
        GLD16(vgA + (t0), vd);                                       \
        GLD16(vgB + (t0), vd + 1024);                                \
    } while (0)

    float mrun0 = -1e30f, mrun1 = -1e30f, lrun0 = 0.f, lrun1 = 0.f;
    f32x4 o0[4] = {}, o1[4] = {};
    int kxor = l15 & 7;
    int vxor = (l15 >> 1) & 3;
    int srcA = l15 + ((l4 & 1) * 2) * 16, srcB = srcA + 16;
    int sel = l4 >> 1;

    STAGE(0, T0C(g));

    for (int i = 0; i < niter; ++i) {
        int bi = i & 1;
        __syncthreads();                      // buf bi ready; bi^1 free
        if (i + 1 < niter) STAGE(bi ^ 1, T0C(4 * (i + 1) + g));

        const f16* Kt = KV + (g * 2 + bi) * 2048;
        const f16* Vt = KV + 16384 + (g * 2 + bi) * 2048;

        // QK^T both fragments, K reads shared: st[m][n], tok = n*16+l4*4+r, q-col = l15
        f32x4 s00 = {}, s01 = {}, s10 = {}, s11 = {};
        __builtin_amdgcn_s_setprio(1);
#pragma unroll
        for (int kk = 0; kk < 2; ++kk) {
            f16x8 ka0 = *(const f16x8*)&Kt[(0 * 16 + l15) * 64 + (((kk * 4 + l4) ^ kxor) << 3)];
            f16x8 ka1 = *(const f16x8*)&Kt[(1 * 16 + l15) * 64 + (((kk * 4 + l4) ^ kxor) << 3)];
            s00 = mfma16(ka0, qf0[kk], s00);
            s10 = mfma16(ka0, qf1[kk], s10);
            s01 = mfma16(ka1, qf0[kk], s01);
            s11 = mfma16(ka1, qf1[kk], s11);
        }
        __builtin_amdgcn_s_setprio(0);

        union PK { f16 h[4]; long long ll; };
        union PB { long long ll[2]; f16x8 v; } pb0, pb1;
        // ---- softmax fragment 0 ----
        {
            f32x4 mm;
#pragma unroll
            for (int r = 0; r < 4; ++r) mm[r] = fmaxf(s00[r], s01[r]);
            float mx = fmaxf(fmaxf(mm[0], mm[1]), fmaxf(mm[2], mm[3]));
            mx = fmaxf(mx, __shfl_xor(mx, 16));
            mx = fmaxf(mx, __shfl_xor(mx, 32));
            float mnew = fmaxf(mrun0, mx);
            float alpha = __expf(mrun0 - mnew);
            mrun0 = mnew;
            float rs = 0.f;
            PK pk0, pk1;
#pragma unroll
            for (int r = 0; r < 4; ++r) {
                float p0 = __expf(s00[r] - mnew), p1 = __expf(s01[r] - mnew);
                rs += p0 + p1;
                pk0.h[r] = (f16)p0; pk1.h[r] = (f16)p1;
            }
            rs += __shfl_xor(rs, 16);
            rs += __shfl_xor(rs, 32);
            lrun0 = lrun0 * alpha + rs;
#pragma unroll
            for (int nd = 0; nd < 4; ++nd) o0[nd] *= alpha;
            long long A0 = __shfl(pk0.ll, srcA), A1 = __shfl(pk1.ll, srcA);
            long long B0 = __shfl(pk0.ll, srcB), B1 = __shfl(pk1.ll, srcB);
            pb0.ll[0] = sel ? A1 : A0;
            pb0.ll[1] = sel ? B1 : B0;
        }
        // ---- softmax fragment 1 ----
        {
            f32x4 mm;
#pragma unroll
            for (int r = 0; r < 4; ++r) mm[r] = fmaxf(s10[r], s11[r]);
            float mx = fmaxf(fmaxf(mm[0], mm[1]), fmaxf(mm[2], mm[3]));
            mx = fmaxf(mx, __shfl_xor(mx, 16));
            mx = fmaxf(mx, __shfl_xor(mx, 32));
            float mnew = fmaxf(mrun1, mx);
            float alpha = __expf(mrun1 - mnew);
            mrun1 = mnew;
            float rs = 0.f;
            PK pk0, pk1;
#pragma unroll
            for (int r = 0; r < 4; ++r) {
                float p0 = __expf(s10[r] - mnew), p1 = __expf(s11[r] - mnew);
                rs += p0 + p1;
                pk0.h[r] = (f16)p0; pk1.h[r] = (f16)p1;
            }
            rs += __shfl_xor(rs, 16);
            rs += __shfl_xor(rs, 32);
            lrun1 = lrun1 * alpha + rs;
#pragma unroll
            for (int nd = 0; nd < 4; ++nd) o1[nd] *= alpha;
            long long A0 = __shfl(pk0.ll, srcA), A1 = __shfl(pk1.ll, srcA);
            long long B0 = __shfl(pk0.ll, srcB), B1 = __shfl(pk1.ll, srcB);
            pb1.ll[0] = sel ? A1 : A0;
            pb1.ll[1] = sel ? B1 : B0;
        }
        // ---- PV, V reads shared ----
        __builtin_amdgcn_s_setprio(1);
#pragma unroll
        for (int nd = 0; nd < 4; ++nd) {
            f16x8 va = *(const f16x8*)&Vt[(nd * 16 + l15) * 32 + ((l4 ^ vxor) << 3)];
            o0[nd] = mfma16(va, pb0.v, o0[nd]);
            o1[nd] = mfma16(va, pb1.v, o1[nd]);
        }
        __builtin_amdgcn_s_setprio(0);
    }
#undef STAGE
#undef T0C

    // ---- publish partials (all groups) ----
    __syncthreads();                          // everyone done with K/V tiles
    float* mg = (float*)KV;                   // [g][q 64][d 64] f32 = 64KB
    int q0 = qs * 32 + l15;
    if (l4 == 0) {
        ML[g * 64 + q0] = mrun0;       ML[256 + g * 64 + q0] = lrun0;
        ML[g * 64 + q0 + 16] = mrun1;  ML[256 + g * 64 + q0 + 16] = lrun1;
    }
    {
        int xr0 = (q0 & 7) << 2, q1 = q0 + 16, xr1 = (q1 & 7) << 2;
#pragma unroll
        for (int nd = 0; nd < 4; ++nd) {
            *(f32x4*)&mg[g * 4096 + q0 * 64 + ((nd * 16 + l4 * 4) ^ xr0)] = o0[nd];
            *(f32x4*)&mg[g * 4096 + q1 * 64 + ((nd * 16 + l4 * 4) ^ xr1)] = o1[nd];
        }
    }
    __syncthreads();

    // ---- distributed 4-way merge; 16B coalesced ao stores ----
    {
        int qq = l15 + l4 * 16;               // 0..63
        float m0 = ML[qq], m1 = ML[64 + qq], m2 = ML[128 + qq], m3 = ML[192 + qq];
        float M = fmaxf(fmaxf(m0, m1), fmaxf(m2, m3));
        float e0 = __expf(m0 - M), e1 = __expf(m1 - M), e2 = __expf(m2 - M), e3 = __expf(m3 - M);
        float L = ML[256 + qq] * e0 + ML[320 + qq] * e1 + ML[384 + qq] * e2 + ML[448 + qq] * e3;
        float inv = 1.f / L;
        int xr = (qq & 7) << 2;
        int Aoff = (wid * 8) ^ xr;            // j 0..3 at Aoff+j; j 4..7 at (Aoff^4)+(j-4)
        f32x4 accA = {}, accB = {};
#pragma unroll
        for (int gg = 0; gg < 4; ++gg) {
            float eg = gg == 0 ? e0 : gg == 1 ? e1 : gg == 2 ? e2 : e3;
            f32x4 pa = *(const f32x4*)&mg[gg * 4096 + qq * 64 + Aoff];
            f32x4 pc = *(const f32x4*)&mg[gg * 4096 + qq * 64 + (Aoff ^ 4)];
#pragma unroll
            for (int r = 0; r < 4; ++r) { accA[r] += eg * pa[r]; accB[r] += eg * pc[r]; }
        }
        union { f16 h[8]; f16x8 v; } w;
#pragma unroll
        for (int r = 0; r < 4; ++r) {
            w.h[r] = (f16)(accA[r] * inv);
            w.h[4 + r] = (f16)(accB[r] * inv);
        }
        *(f16x8*)&ao[(size_t)(b * 1024 + qbase + qq) * 512 + hh * 64 + wid * 8] = w.v;
    }
}

// ---- out GEMM: 64x128 tile, LDS dbuf, single barrier/K-step, swizzled ----
__global__ __launch_bounds__(256, 3) void k_gemm_out(
    const f16* __restrict__ A, const f16* __restrict__ Bt, const int* __restrict__ mlab,
    const float* __restrict__ bias, float* __restrict__ out)
{
    __shared__ f16 As[2][64 * 64];
    __shared__ f16 Bs[2][128 * 64];
    int tid = threadIdx.x, wid = tid >> 6, lane = tid & 63;
    int wm = wid >> 1, wn = wid & 1;
    int l15 = lane & 15, l4 = lane >> 4;
    int rowBase = blockIdx.y * 64;
    int colBase = blockIdx.x * 128;
    if (mlab[(rowBase >> 10) * 4 + ((rowBase & 1023) >> 8)] == 0) {
        for (int i = tid; i < 64 * 128; i += 256)
            out[(size_t)(rowBase + (i >> 7)) * 512 + colBase + (i & 127)] = bias[colBase + (i & 127)];
        return;
    }

    int srow = lane >> 3;
    int scolz = ((lane & 7) ^ srow) << 3;
    int kxor = (l15 & 7) << 3;

#define STG(bi, kt)                                                                         \
    do {                                                                                    \
        _Pragma("unroll") for (int i_ = 0; i_ < 2; ++i_) {                                  \
            int rg = (wid * 2 + i_) * 8;                                                    \
            GLD16(&A[(size_t)(rowBase + rg + srow) * 512 + (kt) + scolz], &As[bi][rg * 64]);\
        }                                                                                   \
        _Pragma("unroll") for (int i_ = 0; i_ < 4; ++i_) {                                  \
            int rg = (wid * 4 + i_) * 8;                                                    \
            GLD16(&Bt[(size_t)(colBase + rg + srow) * 512 + (kt) + scolz], &Bs[bi][rg * 64]);\
        }                                                                                   \
    } while (0)

    f32x4 acc[2][4] = {};
    STG(0, 0);
    for (int ki = 0; ki < 8; ++ki) {
        int bi = ki & 1;
        __syncthreads();
        if (ki < 7) STG(bi ^ 1, (ki + 1) * 64);
#pragma unroll
        for (int kk = 0; kk < 2; ++kk) {
            f16x8 af[2], bf[4];
#pragma unroll
            for (int m = 0; m < 2; ++m)
                af[m] = *(const f16x8*)&As[bi][(wm * 32 + m * 16 + l15) * 64 + ((kk * 32 + l4 * 8) ^ kxor)];
#pragma unroll
            for (int n = 0; n < 4; ++n)
                bf[n] = *(const f16x8*)&Bs[bi][(wn * 64 + n * 16 + l15) * 64 + ((kk * 32 + l4 * 8) ^ kxor)];
#pragma unroll
            for (int m = 0; m < 2; ++m)
#pragma unroll
                for (int n = 0; n < 4; ++n)
                    acc[m][n] = mfma16(af[m], bf[n], acc[m][n]);
        }
    }
#undef STG
#pragma unroll
    for (int m = 0; m < 2; ++m)
#pragma unroll
        for (int n = 0; n < 4; ++n)
#pragma unroll
            for (int r = 0; r < 4; ++r) {
                int row = rowBase + wm * 32 + m * 16 + l4 * 4 + r;
                int col = colBase + wn * 64 + n * 16 + l15;
                out[(size_t)row * 512 + col] = acc[m][n][r] + bias[col];
            }
}

extern "C" void kernel_launch(void* const* d_in, const int* in_sizes, int n_in,
                              void* d_out, int out_size, void* d_ws, size_t ws_size,
                              hipStream_t stream) {
    const float* x     = (const float*)d_in[0];
    const int*   mlab  = (const int*)d_in[1];
    const float* gamma = (const float*)d_in[2];
    const float* beta  = (const float*)d_in[3];
    const float* wqkv  = (const float*)d_in[4];
    const float* wout  = (const float*)d_in[5];
    const float* bout  = (const float*)d_in[6];
    float* out = (float*)d_out;

    f16* h     = (f16*)d_ws;                 // 8192*512
    f16* wqkvT = h + 8192 * 512;             // 1536*512
    f16* woutT = wqkvT + 1536 * 512;         // 512*512
    f16* q     = woutT + 512 * 512;          // [B*H][1024][64]
    f16* kmat  = q + 4 * 1024 * 1024;
    f16* vt    = kmat + 4 * 1024 * 1024;     // [B*H][64][1024]
    f16* ao    = h;                          // h dead after QKV GEMM -> reuse

    k_prep<<<2304, 256, 0, stream>>>(x, gamma, beta, mlab, wqkv, wout, h, wqkvT, woutT);
    k_gemm_qkv<<<dim3(12, 128), 256, 0, stream>>>(h, wqkvT, mlab, q, kmat, vt);
    k_attn<<<1024, 512, 0, stream>>>(q, kmat, vt, mlab, ao);
    k_gemm_out<<<dim3(4, 128), 256, 0, stream>>>(ao, woutT, mlab, bout, out);
}